// Round 7
// baseline (3417.814 us; speedup 1.0000x reference)
//
#include <hip/hip_runtime.h>

#define T_   500
#define B_   32
#define IN_  512
#define H_   1024
#define NWG  128    // total WGs (64 per direction)
#define NPD  64     // WGs per direction
#define THR  512    // threads per WG (8 waves)

typedef _Float16 f16x8 __attribute__((ext_vector_type(8)));
typedef float    f32x4 __attribute__((ext_vector_type(4)));

#define MFMA __builtin_amdgcn_mfma_f32_16x16x32_f16

// counted vmem wait + scheduling fence (rule #18: uses must not slip past the wait)
#define WAITV(N) do { asm volatile("s_waitcnt vmcnt(" #N ")" ::: "memory"); \
                      __builtin_amdgcn_sched_barrier(0); } while (0)

// canary poll load (single dword, MALL bypass)
#define CANISS(r) \
  asm volatile("global_load_dword %0, %1, off sc0 sc1" \
               : "=v"(cw##r) : "v"(cPtr) : "memory")

// conditional coherent (MALL-bypass) bulk load of one dwordx4 of packed {tag|h} words
#define PISS(r, off) do { if (!(done & (1u << (r)))) \
  asm volatile("global_load_dwordx4 %0, %1, off offset:" #off " sc0 sc1" \
               : "=v"(q##r) : "v"(aH) : "memory"); } while (0)

// validate tags of one dwordx4 (tag in high 16 bits of every word)
#define PCHK(r) do { if (!(done & (1u << (r)))) { \
  unsigned bad_ = ((q##r.x ^ tagw) | (q##r.y ^ tagw) | (q##r.z ^ tagw) | (q##r.w ^ tagw)) \
                  & 0xFFFF0000u; \
  if (bad_ == 0u) done |= (1u << (r)); } } while (0)

// build f16x8 A-fragment from two validated dwordx4 (h in low 16 of each word)
#define HPACK(dst, qa, qb) do { \
  uint4 t_ = { (qa.x & 0xFFFFu) | (qa.y << 16), (qa.z & 0xFFFFu) | (qa.w << 16), \
               (qb.x & 0xFFFFu) | (qb.y << 16), (qb.z & 0xFFFFu) | (qb.w << 16) }; \
  dst = __builtin_bit_cast(f16x8, t_); } while (0)

// one h k-step: A-frag against 4 n-tile B-frags from swizzled LDS
#define HSTEP(hf, ks) do { \
  const int t_ = (kq512 + (ks) * 64 + fkb16) ^ sw; \
  acc0 = MFMA(hf, *(const f16x8*)(WhB0 + t_), acc0, 0, 0, 0); \
  acc1 = MFMA(hf, *(const f16x8*)(WhB1 + t_), acc1, 0, 0, 0); \
  acc2 = MFMA(hf, *(const f16x8*)(WhB2 + t_), acc2, 0, 0, 0); \
  acc3 = MFMA(hf, *(const f16x8*)(WhB3 + t_), acc3, 0, 0, 0); } while (0)

__device__ __forceinline__ f16x8 cvt8(float4 lo, float4 hi) {
  return (f16x8){ (_Float16)lo.x, (_Float16)lo.y, (_Float16)lo.z, (_Float16)lo.w,
                  (_Float16)hi.x, (_Float16)hi.y, (_Float16)hi.z, (_Float16)hi.w };
}

// ---------------------------------------------------------------- x -> fp16
__global__ void cvt_x_kernel(const float* __restrict__ x, _Float16* __restrict__ xb, int n8) {
  int i = blockIdx.x * blockDim.x + threadIdx.x;
  if (i >= n8) return;
  const float4* p = (const float4*)x + (size_t)i * 2;
  *((f16x8*)xb + i) = cvt8(p[0], p[1]);
}

// ---------------------------------------------------------------- persistent LSTM
__global__ __launch_bounds__(THR, 1) void lstm_kernel(
    const float* __restrict__ w_ih_f, const float* __restrict__ w_hh_f,
    const float* __restrict__ b_ih_f, const float* __restrict__ b_hh_f,
    const float* __restrict__ w_ih_r, const float* __restrict__ w_hh_r,
    const float* __restrict__ b_ih_r, const float* __restrict__ b_hh_r,
    const _Float16* __restrict__ xb, unsigned* __restrict__ hbw,
    float* __restrict__ out)
{
  __shared__ _Float16 Wh[64 * 1024];   // 131,072 B : h-weights, XOR-swizzled rows
  __shared__ float    pg[4][32][64];   //  32,768 B : K-quarter partial gates
  // total 163,840 B = 160 KiB (device max)

  const int wg   = blockIdx.x;
  const int dir  = wg >> 6;
  const int slot = wg & 63;
  const int col0 = slot * 16;          // first owned h-column (16 per WG)
  const int tid  = threadIdx.x;

  const float* w_ih = dir ? w_ih_r : w_ih_f;
  const float* w_hh = dir ? w_hh_r : w_hh_f;
  const float* b_ih = dir ? b_ih_r : b_ih_f;
  const float* b_hh = dir ? b_hh_r : b_hh_f;

  // ---- stage h-weights into LDS, fp16, row r -> gate row (r>>4)*H + col0 + (r&15),
  //      byte offset r*2048 + ((k*2) ^ ((r&7)<<4))  (swizzled, 16B-aligned)
  for (int i = tid; i < 64 * 128; i += THR) {
    const int r  = i >> 7;
    const int k  = (i & 127) * 8;
    const int gr = (r >> 4) * H_ + col0 + (r & 15);
    const float4* p = (const float4*)(w_hh + (size_t)gr * H_ + k);
    const int byte = r * 2048 + ((k * 2) ^ ((r & 7) << 4));
    *(f16x8*)((char*)Wh + byte) = cvt8(p[0], p[1]);
  }

  // ---- wave tiling: wave = (m-half, K-quarter); each wave does all 4 n-tiles ----
  const int lane = tid & 63, wv = tid >> 6;
  const int mh = wv & 1, kq = wv >> 1;       // m-half (batch), K-quarter
  const int frow = lane & 15, fkb = lane >> 4;
  const int mrow = mh * 16 + frow;           // batch row this lane supplies
  const int sw    = (frow & 7) << 4;         // LDS row swizzle
  const int kq512 = kq * 512;                // h k-quarter byte base in LDS row
  const int fkb16 = fkb * 16;
  const char* WhB0 = (const char*)Wh + (size_t)( 0 + frow) * 2048;
  const char* WhB1 = (const char*)Wh + (size_t)(16 + frow) * 2048;
  const char* WhB2 = (const char*)Wh + (size_t)(32 + frow) * 2048;
  const char* WhB3 = (const char*)Wh + (size_t)(48 + frow) * 2048;

  // ---- x-weights: resident in registers (16 B-frags = 64 VGPRs), fp32 -> fp16 once
  f16x8 xw0[4], xw1[4], xw2[4], xw3[4];
#pragma unroll
  for (int ks = 0; ks < 4; ++ks) {
    const int k = kq * 128 + ks * 32 + fkb * 8;
    { const float4* p = (const float4*)(w_ih + (size_t)(0 * H_ + col0 + frow) * IN_ + k);
      xw0[ks] = cvt8(p[0], p[1]); }
    { const float4* p = (const float4*)(w_ih + (size_t)(1 * H_ + col0 + frow) * IN_ + k);
      xw1[ks] = cvt8(p[0], p[1]); }
    { const float4* p = (const float4*)(w_ih + (size_t)(2 * H_ + col0 + frow) * IN_ + k);
      xw2[ks] = cvt8(p[0], p[1]); }
    { const float4* p = (const float4*)(w_ih + (size_t)(3 * H_ + col0 + frow) * IN_ + k);
      xw3[ks] = cvt8(p[0], p[1]); }
  }

  // ---- per-thread (b, h-col) ownership for gates/state ----
  const int tb = tid >> 4, thc = tid & 15, tcol = col0 + thc;
  const float b0 = b_ih[0 * H_ + tcol] + b_hh[0 * H_ + tcol];
  const float b1 = b_ih[1 * H_ + tcol] + b_hh[1 * H_ + tcol];
  const float b2 = b_ih[2 * H_ + tcol] + b_hh[2 * H_ + tcol];
  const float b3 = b_ih[3 * H_ + tcol] + b_hh[3 * H_ + tcol];
  float c = 0.f;

  __syncthreads();   // weights staged

  for (int s = 0; s < T_; ++s) {
    const int tx = dir ? (T_ - 1 - s) : s;

    // ===== phase 1: x-part — cached A loads, register B =====
    const _Float16* aX = xb + ((size_t)tx * B_ + mrow) * IN_ + kq * 128 + fkb * 8;
    f32x4 acc0 = {0,0,0,0}, acc1 = {0,0,0,0}, acc2 = {0,0,0,0}, acc3 = {0,0,0,0};
#pragma unroll
    for (int ks = 0; ks < 4; ++ks) {
      f16x8 xa = *(const f16x8*)(aX + ks * 32);
      acc0 = MFMA(xa, xw0[ks], acc0, 0, 0, 0);
      acc1 = MFMA(xa, xw1[ks], acc1, 0, 0, 0);
      acc2 = MFMA(xa, xw2[ks], acc2, 0, 0, 0);
      acc3 = MFMA(xa, xw3[ks], acc3, 0, 0, 0);
    }

    if (s > 0) {
      const unsigned* bufb = hbw + (size_t)(dir * 2 + (s & 1)) * B_ * H_;
      const unsigned tagw = (unsigned)s << 16;

      // ===== phase 2a: canary poll — 64 dwords (one per writer WG), depth-2 pipelined =====
      {
        const unsigned* cPtr = bufb + lane * 16;   // batch 0, col = lane*16
        unsigned cw0 = 0, cw1 = 0;
        int guard = 0;
        CANISS(0); CANISS(1);
        for (;;) {
          WAITV(1);   // cw0 ready
          if (__all((cw0 >> 16) == (unsigned)s)) { WAITV(0); break; }
          CANISS(0);
          WAITV(1);   // cw1 ready
          if (__all((cw1 >> 16) == (unsigned)s)) { WAITV(0); break; }
          CANISS(1);
          if (++guard > (1 << 20)) { WAITV(0); break; }   // failsafe: fail loud, not hang
        }
      }

      // ===== phase 2b: single validated bulk load (+ rare straggler repair) =====
      const unsigned* aH = bufb + (size_t)mrow * H_ + kq * 256 + fkb * 8;
      uint4 q0, q1, q2, q3, q4, q5, q6, q7, q8, q9, q10, q11, q12, q13, q14, q15;
      unsigned done = 0;
      int guard = 0;
      for (;;) {
        PISS( 0,   0); PISS( 1,  16); PISS( 2, 128); PISS( 3, 144);
        PISS( 4, 256); PISS( 5, 272); PISS( 6, 384); PISS( 7, 400);
        PISS( 8, 512); PISS( 9, 528); PISS(10, 640); PISS(11, 656);
        PISS(12, 768); PISS(13, 784); PISS(14, 896); PISS(15, 912);
        WAITV(0);
        PCHK( 0); PCHK( 1); PCHK( 2); PCHK( 3);
        PCHK( 4); PCHK( 5); PCHK( 6); PCHK( 7);
        PCHK( 8); PCHK( 9); PCHK(10); PCHK(11);
        PCHK(12); PCHK(13); PCHK(14); PCHK(15);
        if (__all(done == 0xFFFFu)) break;
        if (++guard > (1 << 16)) break;   // failsafe: fail loud, not hang
      }

      // ===== phase 3: h MFMAs — extract fp16 fragments and multiply =====
      f16x8 hf;
      HPACK(hf, q0,  q1 ); HSTEP(hf, 0);
      HPACK(hf, q2,  q3 ); HSTEP(hf, 1);
      HPACK(hf, q4,  q5 ); HSTEP(hf, 2);
      HPACK(hf, q6,  q7 ); HSTEP(hf, 3);
      HPACK(hf, q8,  q9 ); HSTEP(hf, 4);
      HPACK(hf, q10, q11); HSTEP(hf, 5);
      HPACK(hf, q12, q13); HSTEP(hf, 6);
      HPACK(hf, q14, q15); HSTEP(hf, 7);
    }

    // ===== partial-gate write: [kq][m][n], D layout col=lane&15, row=(lane>>4)*4+i =====
#pragma unroll
    for (int i = 0; i < 4; ++i) {
      const int m = mh * 16 + fkb * 4 + i;
      pg[kq][m][ 0 + frow] = acc0[i];
      pg[kq][m][16 + frow] = acc1[i];
      pg[kq][m][32 + frow] = acc2[i];
      pg[kq][m][48 + frow] = acc3[i];
    }
    __syncthreads();

    // ===== phase 4: gates / state update (thread = (batch tb, col thc)) =====
    float xi = pg[0][tb][ 0 + thc] + pg[1][tb][ 0 + thc] + pg[2][tb][ 0 + thc] + pg[3][tb][ 0 + thc] + b0;
    float xf = pg[0][tb][16 + thc] + pg[1][tb][16 + thc] + pg[2][tb][16 + thc] + pg[3][tb][16 + thc] + b1;
    float xg = pg[0][tb][32 + thc] + pg[1][tb][32 + thc] + pg[2][tb][32 + thc] + pg[3][tb][32 + thc] + b2;
    float xo = pg[0][tb][48 + thc] + pg[1][tb][48 + thc] + pg[2][tb][48 + thc] + pg[3][tb][48 + thc] + b3;
    float ig = fminf(fmaxf(0.2f * xi + 0.5f, 0.f), 1.f);
    float fg = fminf(fmaxf(0.2f * xf + 0.5f, 0.f), 1.f);
    float cg = fminf(fmaxf(xg, -1.f), 1.f);
    float og = fminf(fmaxf(0.2f * xo + 0.5f, 0.f), 1.f);
    c = fg * c + ig * cg;
    float hv = og * fminf(fmaxf(c, -1.f), 1.f);

    { // fire-and-forget h publish FIRST (latency-critical): packed {tag=s+1 | h_fp16}
      unsigned hword = (unsigned)__builtin_bit_cast(unsigned short, (_Float16)hv)
                     | ((unsigned)(s + 1) << 16);
      unsigned* hp = hbw + ((size_t)(dir * 2 + ((s + 1) & 1)) * B_ + tb) * H_ + tcol;
      asm volatile("global_store_dword %0, %1, off sc0 sc1" :: "v"(hp), "v"(hword) : "memory");
    }
    out[((size_t)tx * B_ + tb) * (2 * H_) + dir * H_ + tcol] = hv;   // plain cached store
    if (s == T_ - 1) {
      const size_t HY = (size_t)T_ * B_ * 2 * H_;
      out[HY + ((size_t)dir * B_ + tb) * H_ + tcol] = hv;                           // hy
      out[HY + (size_t)2 * B_ * H_ + ((size_t)dir * B_ + tb) * H_ + tcol] = c;      // cy
    }

    __syncthreads();   // pg WAR protection for next step (intra-WG, cheap)
  }
}

// ---------------------------------------------------------------- launcher
extern "C" void kernel_launch(void* const* d_in, const int* in_sizes, int n_in,
                              void* d_out, int out_size, void* d_ws, size_t ws_size,
                              hipStream_t stream) {
  const float* x      = (const float*)d_in[0];
  const float* w_ih_f = (const float*)d_in[1];
  const float* w_hh_f = (const float*)d_in[2];
  const float* b_ih_f = (const float*)d_in[3];
  const float* b_hh_f = (const float*)d_in[4];
  const float* w_ih_r = (const float*)d_in[5];
  const float* w_hh_r = (const float*)d_in[6];
  const float* b_ih_r = (const float*)d_in[7];
  const float* b_hh_r = (const float*)d_in[8];
  float* out = (float*)d_out;

  char* ws = (char*)d_ws;
  _Float16* xb  = (_Float16*)ws;               // 16,384,000 B  (T*B*IN f16)
  unsigned* hbw = (unsigned*)(ws + 16384000);  //    524,288 B  (2 dir * 2 buf * B * H packed words)

  hipMemsetAsync(hbw, 0, 524288, stream);      // clear tags every launch/replay
  cvt_x_kernel<<<4000, 256, 0, stream>>>(x, xb, 1024000);
  lstm_kernel<<<NWG, THR, 0, stream>>>(w_ih_f, w_hh_f, b_ih_f, b_hh_f,
                                       w_ih_r, w_hh_r, b_ih_r, b_hh_r,
                                       xb, hbw, out);
}

// Round 8
// 3199.392 us; speedup vs baseline: 1.0683x; 1.0683x over previous
//
#include <hip/hip_runtime.h>

#define T_   500
#define B_   32
#define IN_  512
#define H_   1024
#define NWG  128    // total WGs (64 per direction)
#define NPD  64     // WGs per direction
#define THR  512    // threads per WG (8 waves)

typedef _Float16 f16x8 __attribute__((ext_vector_type(8)));
typedef float    f32x4 __attribute__((ext_vector_type(4)));

#define MFMA __builtin_amdgcn_mfma_f32_16x16x32_f16

// counted vmem wait + scheduling fence (rule #18: uses must not slip past the wait)
#define WAITV(N) do { asm volatile("s_waitcnt vmcnt(" #N ")" ::: "memory"); \
                      __builtin_amdgcn_sched_barrier(0); } while (0)

// conditional coherent (MALL-bypass) bulk load of one dwordx4 of packed {tag|h} words
#define PISS(r, off) do { if (!(done & (1u << (r)))) \
  asm volatile("global_load_dwordx4 %0, %1, off offset:" #off " sc0 sc1" \
               : "=v"(q##r) : "v"(aH) : "memory"); } while (0)

// validate tags of one dwordx4 (tag in high 16 bits of every word)
#define PCHK(r) do { if (!(done & (1u << (r)))) { \
  unsigned bad_ = ((q##r.x ^ tagw) | (q##r.y ^ tagw) | (q##r.z ^ tagw) | (q##r.w ^ tagw)) \
                  & 0xFFFF0000u; \
  if (bad_ == 0u) done |= (1u << (r)); } } while (0)

// build f16x8 A-fragment from two validated dwordx4 (h in low 16 of each word)
#define HPACK(dst, qa, qb) do { \
  uint4 t_ = { (qa.x & 0xFFFFu) | (qa.y << 16), (qa.z & 0xFFFFu) | (qa.w << 16), \
               (qb.x & 0xFFFFu) | (qb.y << 16), (qb.z & 0xFFFFu) | (qb.w << 16) }; \
  dst = __builtin_bit_cast(f16x8, t_); } while (0)

// one h k-step: A-frag against 4 n-tile B-frags from swizzled LDS
#define HSTEP(hf, ks) do { \
  const int t_ = (kq512 + (ks) * 64 + fkb16) ^ sw; \
  acc0 = MFMA(hf, *(const f16x8*)(WhB0 + t_), acc0, 0, 0, 0); \
  acc1 = MFMA(hf, *(const f16x8*)(WhB1 + t_), acc1, 0, 0, 0); \
  acc2 = MFMA(hf, *(const f16x8*)(WhB2 + t_), acc2, 0, 0, 0); \
  acc3 = MFMA(hf, *(const f16x8*)(WhB3 + t_), acc3, 0, 0, 0); } while (0)

__device__ __forceinline__ f16x8 cvt8(float4 lo, float4 hi) {
  return (f16x8){ (_Float16)lo.x, (_Float16)lo.y, (_Float16)lo.z, (_Float16)lo.w,
                  (_Float16)hi.x, (_Float16)hi.y, (_Float16)hi.z, (_Float16)hi.w };
}

// ---------------------------------------------------------------- x -> fp16
__global__ void cvt_x_kernel(const float* __restrict__ x, _Float16* __restrict__ xb, int n8) {
  int i = blockIdx.x * blockDim.x + threadIdx.x;
  if (i >= n8) return;
  const float4* p = (const float4*)x + (size_t)i * 2;
  *((f16x8*)xb + i) = cvt8(p[0], p[1]);
}

// ---------------------------------------------------------------- persistent LSTM
__global__ __launch_bounds__(THR, 1) void lstm_kernel(
    const float* __restrict__ w_ih_f, const float* __restrict__ w_hh_f,
    const float* __restrict__ b_ih_f, const float* __restrict__ b_hh_f,
    const float* __restrict__ w_ih_r, const float* __restrict__ w_hh_r,
    const float* __restrict__ b_ih_r, const float* __restrict__ b_hh_r,
    const _Float16* __restrict__ xb, unsigned* __restrict__ hbw,
    float* __restrict__ out)
{
  __shared__ _Float16 Wh[64 * 1024];   // 131,072 B : h-weights, XOR-swizzled rows
  __shared__ float    pg[4][32][64];   //  32,768 B : K-quarter partial gates
  // total 163,840 B = 160 KiB (device max)

  const int wg   = blockIdx.x;
  const int dir  = wg >> 6;
  const int slot = wg & 63;
  const int col0 = slot * 16;          // first owned h-column (16 per WG)
  const int tid  = threadIdx.x;

  const float* w_ih = dir ? w_ih_r : w_ih_f;
  const float* w_hh = dir ? w_hh_r : w_hh_f;
  const float* b_ih = dir ? b_ih_r : b_ih_f;
  const float* b_hh = dir ? b_hh_r : b_hh_f;

  // ---- stage h-weights into LDS, fp16, row r -> gate row (r>>4)*H + col0 + (r&15),
  //      byte offset r*2048 + ((k*2) ^ ((r&7)<<4))  (swizzled, 16B-aligned)
  for (int i = tid; i < 64 * 128; i += THR) {
    const int r  = i >> 7;
    const int k  = (i & 127) * 8;
    const int gr = (r >> 4) * H_ + col0 + (r & 15);
    const float4* p = (const float4*)(w_hh + (size_t)gr * H_ + k);
    const int byte = r * 2048 + ((k * 2) ^ ((r & 7) << 4));
    *(f16x8*)((char*)Wh + byte) = cvt8(p[0], p[1]);
  }

  // ---- wave tiling: wave = (m-half, K-quarter); each wave does all 4 n-tiles ----
  const int lane = tid & 63, wv = tid >> 6;
  const int mh = wv & 1, kq = wv >> 1;       // m-half (batch), K-quarter
  const int frow = lane & 15, fkb = lane >> 4;
  const int mrow = mh * 16 + frow;           // batch row this lane supplies
  const int sw    = (frow & 7) << 4;         // LDS row swizzle
  const int kq512 = kq * 512;                // h k-quarter byte base in LDS row
  const int fkb16 = fkb * 16;
  const char* WhB0 = (const char*)Wh + (size_t)( 0 + frow) * 2048;
  const char* WhB1 = (const char*)Wh + (size_t)(16 + frow) * 2048;
  const char* WhB2 = (const char*)Wh + (size_t)(32 + frow) * 2048;
  const char* WhB3 = (const char*)Wh + (size_t)(48 + frow) * 2048;

  // ---- x-weights: resident in registers (16 B-frags = 64 VGPRs), fp32 -> fp16 once
  f16x8 xw0[4], xw1[4], xw2[4], xw3[4];
#pragma unroll
  for (int ks = 0; ks < 4; ++ks) {
    const int k = kq * 128 + ks * 32 + fkb * 8;
    { const float4* p = (const float4*)(w_ih + (size_t)(0 * H_ + col0 + frow) * IN_ + k);
      xw0[ks] = cvt8(p[0], p[1]); }
    { const float4* p = (const float4*)(w_ih + (size_t)(1 * H_ + col0 + frow) * IN_ + k);
      xw1[ks] = cvt8(p[0], p[1]); }
    { const float4* p = (const float4*)(w_ih + (size_t)(2 * H_ + col0 + frow) * IN_ + k);
      xw2[ks] = cvt8(p[0], p[1]); }
    { const float4* p = (const float4*)(w_ih + (size_t)(3 * H_ + col0 + frow) * IN_ + k);
      xw3[ks] = cvt8(p[0], p[1]); }
  }

  // ---- per-thread (b, h-col) ownership for gates/state ----
  const int tb = tid >> 4, thc = tid & 15, tcol = col0 + thc;
  const float b0 = b_ih[0 * H_ + tcol] + b_hh[0 * H_ + tcol];
  const float b1 = b_ih[1 * H_ + tcol] + b_hh[1 * H_ + tcol];
  const float b2 = b_ih[2 * H_ + tcol] + b_hh[2 * H_ + tcol];
  const float b3 = b_ih[3 * H_ + tcol] + b_hh[3 * H_ + tcol];
  float c = 0.f;

  __syncthreads();   // weights staged

  for (int s = 0; s < T_; ++s) {
    const int tx = dir ? (T_ - 1 - s) : s;

    // ===== phase 1: x-part — cached A loads, register B =====
    const _Float16* aX = xb + ((size_t)tx * B_ + mrow) * IN_ + kq * 128 + fkb * 8;
    f32x4 acc0 = {0,0,0,0}, acc1 = {0,0,0,0}, acc2 = {0,0,0,0}, acc3 = {0,0,0,0};
#pragma unroll
    for (int ks = 0; ks < 4; ++ks) {
      f16x8 xa = *(const f16x8*)(aX + ks * 32);
      acc0 = MFMA(xa, xw0[ks], acc0, 0, 0, 0);
      acc1 = MFMA(xa, xw1[ks], acc1, 0, 0, 0);
      acc2 = MFMA(xa, xw2[ks], acc2, 0, 0, 0);
      acc3 = MFMA(xa, xw3[ks], acc3, 0, 0, 0);
    }

    if (s > 0) {
      // ===== phase 2: speculative bulk issue + paced tag-validated catch =====
      // h(s): tag s, buffer s&1. Per lane: 16 dwordx4 = 64 words (its A-fragments).
      const unsigned* bufb = hbw + (size_t)(dir * 2 + (s & 1)) * B_ * H_;
      const unsigned* aH = bufb + (size_t)mrow * H_ + kq * 256 + fkb * 8;
      const unsigned tagw = (unsigned)s << 16;
      uint4 q0, q1, q2, q3, q4, q5, q6, q7, q8, q9, q10, q11, q12, q13, q14, q15;
      unsigned done = 0;
      int guard = 0;
      // speculative issue: by the time these arrive at the MALL, the step-s
      // publishes (issued ~0.25 us earlier by symmetric WGs) have landed.
      for (;;) {
        PISS( 0,   0); PISS( 1,  16); PISS( 2, 128); PISS( 3, 144);
        PISS( 4, 256); PISS( 5, 272); PISS( 6, 384); PISS( 7, 400);
        PISS( 8, 512); PISS( 9, 528); PISS(10, 640); PISS(11, 656);
        PISS(12, 768); PISS(13, 784); PISS(14, 896); PISS(15, 912);
        WAITV(0);
        PCHK( 0); PCHK( 1); PCHK( 2); PCHK( 3);
        PCHK( 4); PCHK( 5); PCHK( 6); PCHK( 7);
        PCHK( 8); PCHK( 9); PCHK(10); PCHK(11);
        PCHK(12); PCHK(13); PCHK(14); PCHK(15);
        if (__all(done == 0xFFFFu)) break;
        if (++guard > 4096) break;            // failsafe: fail loud, not hang
        __builtin_amdgcn_s_sleep(8);          // pace repair rounds (~0.2 us)
      }

      // ===== phase 3: h MFMAs — extract fp16 fragments and multiply =====
      f16x8 hf;
      HPACK(hf, q0,  q1 ); HSTEP(hf, 0);
      HPACK(hf, q2,  q3 ); HSTEP(hf, 1);
      HPACK(hf, q4,  q5 ); HSTEP(hf, 2);
      HPACK(hf, q6,  q7 ); HSTEP(hf, 3);
      HPACK(hf, q8,  q9 ); HSTEP(hf, 4);
      HPACK(hf, q10, q11); HSTEP(hf, 5);
      HPACK(hf, q12, q13); HSTEP(hf, 6);
      HPACK(hf, q14, q15); HSTEP(hf, 7);
    }

    // ===== partial-gate write: [kq][m][n], D layout col=lane&15, row=(lane>>4)*4+i =====
#pragma unroll
    for (int i = 0; i < 4; ++i) {
      const int m = mh * 16 + fkb * 4 + i;
      pg[kq][m][ 0 + frow] = acc0[i];
      pg[kq][m][16 + frow] = acc1[i];
      pg[kq][m][32 + frow] = acc2[i];
      pg[kq][m][48 + frow] = acc3[i];
    }
    __syncthreads();

    // ===== phase 4: gates / state update (thread = (batch tb, col thc)) =====
    float xi = pg[0][tb][ 0 + thc] + pg[1][tb][ 0 + thc] + pg[2][tb][ 0 + thc] + pg[3][tb][ 0 + thc] + b0;
    float xf = pg[0][tb][16 + thc] + pg[1][tb][16 + thc] + pg[2][tb][16 + thc] + pg[3][tb][16 + thc] + b1;
    float xg = pg[0][tb][32 + thc] + pg[1][tb][32 + thc] + pg[2][tb][32 + thc] + pg[3][tb][32 + thc] + b2;
    float xo = pg[0][tb][48 + thc] + pg[1][tb][48 + thc] + pg[2][tb][48 + thc] + pg[3][tb][48 + thc] + b3;
    float ig = fminf(fmaxf(0.2f * xi + 0.5f, 0.f), 1.f);
    float fg = fminf(fmaxf(0.2f * xf + 0.5f, 0.f), 1.f);
    float cg = fminf(fmaxf(xg, -1.f), 1.f);
    float og = fminf(fmaxf(0.2f * xo + 0.5f, 0.f), 1.f);
    c = fg * c + ig * cg;
    float hv = og * fminf(fmaxf(c, -1.f), 1.f);

    { // fire-and-forget h publish FIRST (latency-critical): packed {tag=s+1 | h_fp16}
      unsigned hword = (unsigned)__builtin_bit_cast(unsigned short, (_Float16)hv)
                     | ((unsigned)(s + 1) << 16);
      unsigned* hp = hbw + ((size_t)(dir * 2 + ((s + 1) & 1)) * B_ + tb) * H_ + tcol;
      asm volatile("global_store_dword %0, %1, off sc0 sc1" :: "v"(hp), "v"(hword) : "memory");
    }
    out[((size_t)tx * B_ + tb) * (2 * H_) + dir * H_ + tcol] = hv;   // plain cached store
    if (s == T_ - 1) {
      const size_t HY = (size_t)T_ * B_ * 2 * H_;
      out[HY + ((size_t)dir * B_ + tb) * H_ + tcol] = hv;                           // hy
      out[HY + (size_t)2 * B_ * H_ + ((size_t)dir * B_ + tb) * H_ + tcol] = c;      // cy
    }

    __syncthreads();   // pg WAR protection for next step (intra-WG, cheap)
  }
}

// ---------------------------------------------------------------- launcher
extern "C" void kernel_launch(void* const* d_in, const int* in_sizes, int n_in,
                              void* d_out, int out_size, void* d_ws, size_t ws_size,
                              hipStream_t stream) {
  const float* x      = (const float*)d_in[0];
  const float* w_ih_f = (const float*)d_in[1];
  const float* w_hh_f = (const float*)d_in[2];
  const float* b_ih_f = (const float*)d_in[3];
  const float* b_hh_f = (const float*)d_in[4];
  const float* w_ih_r = (const float*)d_in[5];
  const float* w_hh_r = (const float*)d_in[6];
  const float* b_ih_r = (const float*)d_in[7];
  const float* b_hh_r = (const float*)d_in[8];
  float* out = (float*)d_out;

  char* ws = (char*)d_ws;
  _Float16* xb  = (_Float16*)ws;               // 16,384,000 B  (T*B*IN f16)
  unsigned* hbw = (unsigned*)(ws + 16384000);  //    524,288 B  (2 dir * 2 buf * B * H packed words)

  hipMemsetAsync(hbw, 0, 524288, stream);      // clear tags every launch/replay
  cvt_x_kernel<<<4000, 256, 0, stream>>>(x, xb, 1024000);
  lstm_kernel<<<NWG, THR, 0, stream>>>(w_ih_f, w_hh_f, b_ih_f, b_hh_f,
                                       w_ih_r, w_hh_r, b_ih_r, b_hh_r,
                                       xb, hbw, out);
}